// Round 3
// baseline (165.405 us; speedup 1.0000x reference)
//
#include <hip/hip_runtime.h>
#include <stdint.h>

#define C      1024
#define NH     16
#define HS     64
#define CT     65536
#define PAST   61440   // CT - WINDOW
#define KEEP   12288   // MIN_KV - WINDOW
#define NCOMP  192     // KEEP/64
#define NSEL   32
#define NB     8192    // selection bins (32KB LDS)

// monotone transform: larger float => smaller u (asc u == desc value)
__device__ __forceinline__ unsigned int desc_key(float f) {
    unsigned int b = __float_as_uint(f);
    return (b >> 31) ? b : (~b & 0x7FFFFFFFu);
}
__device__ __forceinline__ float u_to_f(unsigned int u) {
    unsigned int b = (u & 0x80000000u) ? u : (0x7FFFFFFFu - u);
    return __uint_as_float(b);
}
// monotone linear bin: s descending <-> bin ascending
__device__ __forceinline__ int bin_of(float s, float hi, float scale) {
    int b = (int)((hi - s) * scale);
    return b < 0 ? 0 : (b > NB - 1 ? NB - 1 : b);
}

// ---------------- K1: q/k/v projections (+ zero cs_fix) ----------------------
__global__ void k_proj(const float* __restrict__ x, const float* __restrict__ Wr,
                       const float* __restrict__ Wk, const float* __restrict__ Wv,
                       float* __restrict__ q, float* __restrict__ kn, float* __restrict__ vn,
                       unsigned long long* __restrict__ cs_fix) {
    if (blockIdx.x == 0 && threadIdx.x < 256) cs_fix[threadIdx.x] = 0ull;
    int w = blockIdx.x * (blockDim.x >> 6) + (threadIdx.x >> 6); // 0..3071
    int lane = threadIdx.x & 63;
    int mat = w >> 10, row = w & 1023;
    const float* W = (mat == 0) ? Wr : (mat == 1) ? Wk : Wv;
    const float4* Wrow = (const float4*)(W + (size_t)row * C);
    const float4* x4 = (const float4*)x;
    float acc = 0.f;
#pragma unroll
    for (int i = 0; i < 4; ++i) {
        float4 a = Wrow[i * 64 + lane];
        float4 b = x4[i * 64 + lane];
        acc += a.x * b.x + a.y * b.y + a.z * b.z + a.w * b.w;
    }
#pragma unroll
    for (int off = 32; off; off >>= 1) acc += __shfl_xor(acc, off);
    if (lane == 0) { (mat == 0 ? q : (mat == 1 ? kn : vn))[row] = acc; }
}

// ---------------- K2: per-head raw scores s[h][t] = qh . k_cache[t,h] --------
__global__ void k_scores(const float* __restrict__ kc, const float* __restrict__ q,
                         float* __restrict__ s) {
    int wid = blockIdx.x * (blockDim.x >> 6) + (threadIdx.x >> 6);
    int lane = threadIdx.x & 63;
    int nw = gridDim.x * (blockDim.x >> 6);
    const float4* q4 = (const float4*)q;
    float4 qv[4];
#pragma unroll
    for (int i = 0; i < 4; ++i) qv[i] = q4[i * 64 + lane];
    for (int t = wid; t < CT; t += nw) {
        const float4* row = (const float4*)(kc + (size_t)t * C);
        float acc[4];
#pragma unroll
        for (int i = 0; i < 4; ++i) {
            float4 a = row[i * 64 + lane];
            acc[i] = a.x * qv[i].x + a.y * qv[i].y + a.z * qv[i].z + a.w * qv[i].w;
        }
#pragma unroll
        for (int off = 8; off; off >>= 1) {
#pragma unroll
            for (int i = 0; i < 4; ++i) acc[i] += __shfl_xor(acc[i], off);
        }
        if ((lane & 15) == 0) {
            int g = lane >> 4;
#pragma unroll
            for (int i = 0; i < 4; ++i) s[(size_t)(4 * i + g) * CT + t] = acc[i];
        }
    }
}

// -------- K3: fused per-head selection: minmax/hist/scan/scatter/rank --------
// one block per head; emits stok (exact rank order) + chunk scores (fixed pt)
__global__ __launch_bounds__(1024) void k_select(const float* __restrict__ s,
                                                 unsigned long long* __restrict__ G,
                                                 unsigned short* __restrict__ stok,
                                                 unsigned long long* __restrict__ cs_fix) {
    __shared__ unsigned hist[NB];               // 32KB: counts -> bases -> ends
    __shared__ float redA[16], redB[16];
    __shared__ unsigned wsum[16];
    __shared__ unsigned long long csl[NCOMP];
    __shared__ float sh_hi, sh_sc;
    __shared__ unsigned sh_T;

    const int h = blockIdx.x, tid = threadIdx.x;
    const int lane = tid & 63, wave = tid >> 6;
    const float* sh = s + (size_t)h * CT;
    unsigned long long* Gh = G + (size_t)h * 65536;

    if (tid < NCOMP) csl[tid] = 0ull;

    // phase 0: block min/max over PAST
    float mn = 3.4e38f, mx = -3.4e38f;
    for (int t = tid; t < PAST; t += 1024) {
        float v = sh[t];
        mn = fminf(mn, v); mx = fmaxf(mx, v);
    }
#pragma unroll
    for (int off = 32; off; off >>= 1) {
        mn = fminf(mn, __shfl_xor(mn, off));
        mx = fmaxf(mx, __shfl_xor(mx, off));
    }
    if (lane == 0) { redA[wave] = mn; redB[wave] = mx; }
    // phase 1: zero hist (no dependency on phase 0 values)
    for (int i = tid; i < NB; i += 1024) hist[i] = 0;
    __syncthreads();
    if (tid == 0) {
        float lo = redA[0], hi2 = redB[0];
        for (int w = 1; w < 16; ++w) { lo = fminf(lo, redA[w]); hi2 = fmaxf(hi2, redB[w]); }
        float r = hi2 - lo;
        sh_hi = hi2;
        sh_sc = (r > 0.f) ? (float)(NB - 1) / r : 0.f;
    }
    __syncthreads();
    const float hi = sh_hi, sc = sh_sc;

    // phase 2: histogram
    for (int t = tid; t < PAST; t += 1024)
        atomicAdd(&hist[bin_of(sh[t], hi, sc)], 1u);
    __syncthreads();

    // phase 3: exclusive scan of hist in place + threshold bin T
    {
        unsigned cnt[8]; unsigned loc = 0; int b0 = tid * 8;
#pragma unroll
        for (int k = 0; k < 8; ++k) { cnt[k] = hist[b0 + k]; loc += cnt[k]; }
        unsigned run = loc;
#pragma unroll
        for (int off = 1; off < 64; off <<= 1) {
            unsigned n = __shfl_up(run, off);
            if (lane >= off) run += n;
        }
        if (lane == 63) wsum[wave] = run;
        __syncthreads();
        if (wave == 0 && lane < 16) {
            unsigned v = wsum[lane];
#pragma unroll
            for (int off = 1; off < 16; off <<= 1) {
                unsigned n = __shfl_up(v, off);
                if (lane >= off) v += n;
            }
            wsum[lane] = v;
        }
        __syncthreads();
        unsigned r = run - loc + (wave ? wsum[wave - 1] : 0u);
#pragma unroll
        for (int k = 0; k < 8; ++k) {
            unsigned c = cnt[k];
            hist[b0 + k] = r;               // own bins only: no cross-thread hazard
            unsigned inc = r + c;
            if (r < KEEP && inc >= KEEP) sh_T = (unsigned)(b0 + k);
            r = inc;
        }
    }
    __syncthreads();
    const unsigned T = sh_T;

    // phase 4: scatter candidates (bins <= T) packed as (desc_key<<16)|tok
    for (int t = tid; t < PAST; t += 1024) {
        float v = sh[t];
        int b = bin_of(v, hi, sc);
        if ((unsigned)b <= T) {
            unsigned pos = atomicAdd(&hist[b], 1u);
            Gh[pos] = ((unsigned long long)desc_key(v) << 16) | (unsigned)t;
        }
    }
    __syncthreads();

    // phase 5: exact rank within bin (hist now holds post-scatter bin ends)
    unsigned ncand = hist[T];
    for (int p = tid; p < (int)ncand; p += 1024) {
        unsigned long long pk = Gh[p];
        unsigned u = (unsigned)(pk >> 16);
        float v = u_to_f(u);
        int b = bin_of(v, hi, sc);
        unsigned start = b ? hist[b - 1] : 0u;
        unsigned end = hist[b];
        unsigned rank = start;
        for (unsigned j = start; j < end; ++j) rank += (Gh[j] < pk) ? 1u : 0u;
        if (rank < KEEP) {
            stok[h * KEEP + rank] = (unsigned short)(pk & 0xFFFFull);
            long long f = llrintf(v * 16777216.f);
            atomicAdd(&csl[rank >> 6], (unsigned long long)f);
        }
    }

    // phase 6: window-chunk partial sums (wave-aligned: one chunk per wave-iter)
#pragma unroll
    for (int k = 0; k < 4; ++k) {
        int i = tid + k * 1024;                 // 0..4095
        float v = sh[PAST + i];
        long long f = llrintf(v * 16777216.f);
#pragma unroll
        for (int off = 32; off; off >>= 1) f += __shfl_xor(f, off);
        if (lane == 0) atomicAdd(&cs_fix[NCOMP + wave + k * 16], (unsigned long long)f);
    }
    __syncthreads();
    // phase 7: flush compacted-chunk partials
    if (tid < NCOMP) atomicAdd(&cs_fix[tid], csl[tid]);
}

// ---------------- K4: top-32 chunks via bitonic sort of 256 ------------------
__global__ void k_top32(const unsigned long long* __restrict__ cs_fix,
                        unsigned int* __restrict__ sel) {
    __shared__ unsigned long long key[256];
    int tid = threadIdx.x;
    long long v = (long long)cs_fix[tid];
    unsigned long long bb = (unsigned long long)(v + (1ll << 45));   // strictly positive
    key[tid] = (((1ull << 46) - bb) << 8) | (unsigned)tid;           // asc key == (val desc, idx asc)
    __syncthreads();
    for (unsigned k = 2; k <= 256; k <<= 1) {
        for (unsigned j = k >> 1; j > 0; j >>= 1) {
            unsigned ixj = tid ^ j;
            if (ixj > (unsigned)tid) {
                unsigned long long a = key[tid], b = key[ixj];
                bool up = ((tid & k) == 0);
                bool sw = up ? (a > b) : (a < b);
                if (sw) { key[tid] = b; key[ixj] = a; }
            }
            __syncthreads();
        }
    }
    if (tid < NSEL) sel[tid] = (unsigned int)(key[tid] & 0xFFull);
}

// ---------------- K5a: per (head, selected chunk) partial softmax+PV ---------
__global__ void k_attn_part(const float* __restrict__ s, const float* __restrict__ vc,
                            const unsigned short* __restrict__ stok,
                            const unsigned int* __restrict__ sel,
                            float* __restrict__ part) {
    int h = blockIdx.x >> 5, ci = blockIdx.x & 31;
    int tid = threadIdx.x;     // 256
    int g = tid >> 2, b3 = tid & 3;
    int c = (int)sel[ci];
    int t = (c < NCOMP) ? (int)stok[h * KEEP + c * 64 + g]
                        : (PAST + (c - NCOMP) * 64 + g);
    __shared__ float scm[64];
    __shared__ float ex[64];
    __shared__ float vbuf[64][65];
    if (b3 == 0) scm[g] = s[(size_t)h * CT + t] * 0.125f;
    __syncthreads();
    float m = -1e30f;
    for (int j = 0; j < 64; ++j) m = fmaxf(m, scm[j]);
    float e = expf(scm[g] - m);
    const float4* vrow = (const float4*)(vc + (size_t)t * C + h * HS);
#pragma unroll
    for (int it = 0; it < 4; ++it) {
        float4 vv = vrow[it * 4 + b3];
        int d0 = it * 16 + b3 * 4;
        vbuf[g][d0 + 0] = e * vv.x;
        vbuf[g][d0 + 1] = e * vv.y;
        vbuf[g][d0 + 2] = e * vv.z;
        vbuf[g][d0 + 3] = e * vv.w;
    }
    if (b3 == 0) ex[g] = e;
    __syncthreads();
    if (tid < 64) {
        float acc = 0.f;
        for (int g2 = 0; g2 < 64; ++g2) acc += vbuf[g2][tid];
        float* P = part + (size_t)(h * 32 + ci) * 68;
        P[2 + tid] = acc;
        if (tid == 0) {
            float es = 0.f;
            for (int g2 = 0; g2 < 64; ++g2) es += ex[g2];
            P[0] = m;
            P[1] = es;
        }
    }
}

// ---------------- K5b: combine partials + new token -> y ---------------------
__global__ void k_attn_fin(const float* __restrict__ part, const float* __restrict__ q,
                           const float* __restrict__ kn, const float* __restrict__ vn,
                           float* __restrict__ y) {
    int h = blockIdx.x;
    int lane = threadIdx.x;   // 64
    float qd = q[h * HS + lane] * kn[h * HS + lane];
#pragma unroll
    for (int off = 32; off; off >>= 1) qd += __shfl_xor(qd, off);
    float a_new = qd * 0.125f;
    const float* P0 = part + (size_t)h * 32 * 68;
    float m = a_new;
    for (int ci = 0; ci < 32; ++ci) m = fmaxf(m, P0[ci * 68]);
    float den = expf(a_new - m);
    float acc = den * vn[h * HS + lane];
    for (int ci = 0; ci < 32; ++ci) {
        float w = expf(P0[ci * 68] - m);
        den += w * P0[ci * 68 + 1];
        acc += w * P0[ci * 68 + 2 + lane];
    }
    y[h * HS + lane] = acc / den;
}

// ---------------- K6: out = y @ Wo.T -----------------------------------------
__global__ void k_out(const float* __restrict__ Wo, const float* __restrict__ y,
                      float* __restrict__ out) {
    int w = blockIdx.x * (blockDim.x >> 6) + (threadIdx.x >> 6); // 0..1023
    int lane = threadIdx.x & 63;
    const float4* Wrow = (const float4*)(Wo + (size_t)w * C);
    const float4* y4 = (const float4*)y;
    float acc = 0.f;
#pragma unroll
    for (int i = 0; i < 4; ++i) {
        float4 a = Wrow[i * 64 + lane];
        float4 b = y4[i * 64 + lane];
        acc += a.x * b.x + a.y * b.y + a.z * b.z + a.w * b.w;
    }
#pragma unroll
    for (int off = 32; off; off >>= 1) acc += __shfl_xor(acc, off);
    if (lane == 0) out[w] = acc;
}

extern "C" void kernel_launch(void* const* d_in, const int* in_sizes, int n_in,
                              void* d_out, int out_size, void* d_ws, size_t ws_size,
                              hipStream_t stream) {
    const float* x  = (const float*)d_in[0];
    const float* kc = (const float*)d_in[1];
    const float* vc = (const float*)d_in[2];
    const float* Wr = (const float*)d_in[3];
    const float* Wk = (const float*)d_in[4];
    const float* Wv = (const float*)d_in[5];
    const float* Wo = (const float*)d_in[6];
    float* out = (float*)d_out;
    char* ws = (char*)d_ws;

    float* q    = (float*)(ws + 0);
    float* kn   = (float*)(ws + 8192);
    float* vn   = (float*)(ws + 16384);
    float* y    = (float*)(ws + 24576);
    unsigned long long* cs_fix = (unsigned long long*)(ws + 32768);  // 256 * 8B
    unsigned int* sel = (unsigned int*)(ws + 40960);
    float* part = (float*)(ws + 49152);                       // 139264 B
    unsigned short* stok = (unsigned short*)(ws + 196608);    // 393216 B
    float* s = (float*)(ws + 1048576);                        // 4 MiB
    unsigned long long* G = (unsigned long long*)(ws + 8388608); // 16*65536*8 = 8 MiB

    k_proj<<<768, 256, 0, stream>>>(x, Wr, Wk, Wv, q, kn, vn, cs_fix);
    k_scores<<<2048, 256, 0, stream>>>(kc, q, s);
    k_select<<<16, 1024, 0, stream>>>(s, G, stok, cs_fix);
    k_top32<<<1, 256, 0, stream>>>(cs_fix, sel);
    k_attn_part<<<512, 256, 0, stream>>>(s, vc, stok, sel, part);
    k_attn_fin<<<16, 64, 0, stream>>>(part, q, kn, vn, y);
    k_out<<<256, 256, 0, stream>>>(Wo, y, out);
}

// Round 4
// 142.840 us; speedup vs baseline: 1.1580x; 1.1580x over previous
//
#include <hip/hip_runtime.h>
#include <stdint.h>

#define C      1024
#define NH     16
#define HS     64
#define CT     65536
#define PAST   61440   // CT - WINDOW
#define KEEP   12288   // MIN_KV - WINDOW
#define NCOMP  192     // KEEP/64
#define NSEL   32
#define NB     8192    // selection bins

// monotone transform: larger float => smaller u (asc u == desc value)
__device__ __forceinline__ unsigned int desc_key(float f) {
    unsigned int b = __float_as_uint(f);
    return (b >> 31) ? b : (~b & 0x7FFFFFFFu);
}
__device__ __forceinline__ float u_to_f(unsigned int u) {
    unsigned int b = (u & 0x80000000u) ? u : (0x7FFFFFFFu - u);
    return __uint_as_float(b);
}
// monotone linear bin: s descending <-> bin ascending
__device__ __forceinline__ int bin_of(float s, float hi, float scale) {
    int b = (int)((hi - s) * scale);
    return b < 0 ? 0 : (b > NB - 1 ? NB - 1 : b);
}
__device__ __forceinline__ void load_params(const unsigned* umin, const unsigned* umax,
                                            int h, float* hi, float* sc) {
    float h2 = u_to_f(umin[h]);
    float lo = u_to_f(umax[h]);
    float r = h2 - lo;
    *hi = h2;
    *sc = (r > 0.f) ? (float)(NB - 1) / r : 0.f;
}

// ---------------- K1: q/k/v projections + all zero-inits ---------------------
__global__ void k_proj(const float* __restrict__ x, const float* __restrict__ Wr,
                       const float* __restrict__ Wk, const float* __restrict__ Wv,
                       float* __restrict__ q, float* __restrict__ kn, float* __restrict__ vn,
                       unsigned* __restrict__ hist, unsigned* __restrict__ umin,
                       unsigned* __restrict__ umax, unsigned long long* __restrict__ cs_fix) {
    int id = blockIdx.x * 256 + threadIdx.x;
    if (id < NH * NB) hist[id] = 0;
    if (blockIdx.x == 700) {
        if (threadIdx.x < 16) umin[threadIdx.x] = 0xFFFFFFFFu;
        else if (threadIdx.x < 32) umax[threadIdx.x - 16] = 0u;
    }
    if (blockIdx.x == 701 && threadIdx.x < 256) cs_fix[threadIdx.x] = 0ull;

    int w = blockIdx.x * (blockDim.x >> 6) + (threadIdx.x >> 6); // 0..3071
    int lane = threadIdx.x & 63;
    int mat = w >> 10, row = w & 1023;
    const float* W = (mat == 0) ? Wr : (mat == 1) ? Wk : Wv;
    const float4* Wrow = (const float4*)(W + (size_t)row * C);
    const float4* x4 = (const float4*)x;
    float acc = 0.f;
#pragma unroll
    for (int i = 0; i < 4; ++i) {
        float4 a = Wrow[i * 64 + lane];
        float4 b = x4[i * 64 + lane];
        acc += a.x * b.x + a.y * b.y + a.z * b.z + a.w * b.w;
    }
#pragma unroll
    for (int off = 32; off; off >>= 1) acc += __shfl_xor(acc, off);
    if (lane == 0) { (mat == 0 ? q : (mat == 1 ? kn : vn))[row] = acc; }
}

// ------- K2: per-head raw scores s[h][t] = qh.k_cache[t,h]  (+minmax) --------
__global__ void k_scores(const float* __restrict__ kc, const float* __restrict__ q,
                         float* __restrict__ s, unsigned* __restrict__ umin,
                         unsigned* __restrict__ umax) {
    __shared__ float smn[4][16], smx[4][16];
    int wid = blockIdx.x * (blockDim.x >> 6) + (threadIdx.x >> 6);
    int lane = threadIdx.x & 63, wave = threadIdx.x >> 6;
    int nw = gridDim.x * (blockDim.x >> 6);
    const float4* q4 = (const float4*)q;
    float4 qv[4];
#pragma unroll
    for (int i = 0; i < 4; ++i) qv[i] = q4[i * 64 + lane];
    float mnv[4] = {3.4e38f, 3.4e38f, 3.4e38f, 3.4e38f};
    float mxv[4] = {-3.4e38f, -3.4e38f, -3.4e38f, -3.4e38f};
    for (int t = wid; t < CT; t += nw) {
        const float4* row = (const float4*)(kc + (size_t)t * C);
        float acc[4];
#pragma unroll
        for (int i = 0; i < 4; ++i) {
            float4 a = row[i * 64 + lane];
            acc[i] = a.x * qv[i].x + a.y * qv[i].y + a.z * qv[i].z + a.w * qv[i].w;
        }
#pragma unroll
        for (int off = 8; off; off >>= 1) {
#pragma unroll
            for (int i = 0; i < 4; ++i) acc[i] += __shfl_xor(acc[i], off);
        }
        if ((lane & 15) == 0) {
            int g = lane >> 4;
#pragma unroll
            for (int i = 0; i < 4; ++i) {
                s[(size_t)(4 * i + g) * CT + t] = acc[i];
                if (t < PAST) {
                    mnv[i] = fminf(mnv[i], acc[i]);
                    mxv[i] = fmaxf(mxv[i], acc[i]);
                }
            }
        }
    }
    if ((lane & 15) == 0) {
        int g = lane >> 4;
#pragma unroll
        for (int i = 0; i < 4; ++i) { smn[wave][4 * i + g] = mnv[i]; smx[wave][4 * i + g] = mxv[i]; }
    }
    __syncthreads();
    if (threadIdx.x < 16) {
        int h = threadIdx.x;
        float mn = smn[0][h], mx = smx[0][h];
        for (int w2 = 1; w2 < 4; ++w2) {
            mn = fminf(mn, smn[w2][h]);
            mx = fmaxf(mx, smx[w2][h]);
        }
        atomicMin(&umin[h], desc_key(mx));   // smallest key == largest value
        atomicMax(&umax[h], desc_key(mn));   // largest key == smallest value
    }
}

// ---------------- S1: linear-bin histogram over PAST (4 blocks/head) ---------
__global__ __launch_bounds__(1024) void s1_hist(const float* __restrict__ s,
                                                unsigned* __restrict__ hist,
                                                const unsigned* __restrict__ umin,
                                                const unsigned* __restrict__ umax) {
    __shared__ unsigned lh[NB];
    int h = blockIdx.x >> 2, seg = blockIdx.x & 3;
    int tid = threadIdx.x;
    for (int i = tid; i < NB; i += 1024) lh[i] = 0;
    __syncthreads();
    float hi, sc; load_params(umin, umax, h, &hi, &sc);
    const float* sh = s + (size_t)h * CT + seg * 15360;
    for (int i = tid; i < 15360; i += 1024)
        atomicAdd(&lh[bin_of(sh[i], hi, sc)], 1u);
    __syncthreads();
    unsigned* gh = hist + h * NB;
    for (int i = tid; i < NB; i += 1024) {
        unsigned c = lh[i];
        if (c) atomicAdd(&gh[i], c);
    }
}

// ------- S2: exclusive scan + threshold bin T  (+ window-chunk sums) ---------
__global__ __launch_bounds__(1024) void s2_scan(unsigned* __restrict__ base,
                                                unsigned* __restrict__ Tarr,
                                                const float* __restrict__ s,
                                                unsigned long long* __restrict__ cs_fix) {
    __shared__ unsigned wsum[16];
    int h = blockIdx.x, tid = threadIdx.x, lane = tid & 63, wave = tid >> 6;
    unsigned* B = base + h * NB;
    unsigned cnt[8];
    unsigned loc = 0;
    int b0 = tid * 8;
#pragma unroll
    for (int k = 0; k < 8; ++k) { cnt[k] = B[b0 + k]; loc += cnt[k]; }
    unsigned run = loc;
#pragma unroll
    for (int off = 1; off < 64; off <<= 1) {
        unsigned n = __shfl_up(run, off);
        if (lane >= off) run += n;
    }
    if (lane == 63) wsum[wave] = run;
    __syncthreads();
    if (wave == 0 && lane < 16) {
        unsigned v = wsum[lane];
#pragma unroll
        for (int off = 1; off < 16; off <<= 1) {
            unsigned n = __shfl_up(v, off);
            if (lane >= off) v += n;
        }
        wsum[lane] = v;
    }
    __syncthreads();
    unsigned r = run - loc + (wave ? wsum[wave - 1] : 0u);
#pragma unroll
    for (int k = 0; k < 8; ++k) {
        unsigned c = cnt[k];
        B[b0 + k] = r;               // own bins only: no cross-thread hazard
        unsigned inc = r + c;
        if (r < KEEP && inc >= KEEP) Tarr[h] = (unsigned)(b0 + k);
        r = inc;
    }
    // window-chunk partial sums (fixed point; wave w, round k -> chunk k*16+w)
    const float* sh = s + (size_t)h * CT;
#pragma unroll
    for (int k = 0; k < 4; ++k) {
        int i = tid + k * 1024;                 // 0..4095
        float v = sh[PAST + i];
        long long f = llrintf(v * 16777216.f);
#pragma unroll
        for (int off = 32; off; off >>= 1) f += __shfl_xor(f, off);
        if (lane == 0) atomicAdd(&cs_fix[NCOMP + k * 16 + wave], (unsigned long long)f);
    }
}

// ---------------- S3: scatter candidates (bins <= T) into G ------------------
__global__ __launch_bounds__(1024) void s3_scatter(const float* __restrict__ s,
                                                   unsigned* __restrict__ base,
                                                   const unsigned* __restrict__ Tarr,
                                                   unsigned long long* __restrict__ G,
                                                   const unsigned* __restrict__ umin,
                                                   const unsigned* __restrict__ umax) {
    int h = blockIdx.x / 60, seg = blockIdx.x % 60;
    int t = seg * 1024 + threadIdx.x;   // < 61440
    float hi, sc; load_params(umin, umax, h, &hi, &sc);
    float v = s[(size_t)h * CT + t];
    int b = bin_of(v, hi, sc);
    if ((unsigned)b <= Tarr[h]) {
        unsigned pos = atomicAdd(&base[h * NB + b], 1u);
        G[(size_t)h * 65536 + pos] = ((unsigned long long)desc_key(v) << 16) | (unsigned)t;
    }
}

// ------ S4: exact rank within bin; emit stok + compacted chunk sums ----------
__global__ __launch_bounds__(1024) void s4_rank(const unsigned* __restrict__ base,
                                                const unsigned* __restrict__ Tarr,
                                                const unsigned long long* __restrict__ G,
                                                const unsigned* __restrict__ umin,
                                                const unsigned* __restrict__ umax,
                                                unsigned short* __restrict__ stok,
                                                unsigned long long* __restrict__ cs_fix) {
    __shared__ unsigned long long csl[NCOMP];
    int h = blockIdx.x >> 4, seg = blockIdx.x & 15;
    int tid = threadIdx.x;
    if (tid < NCOMP) csl[tid] = 0ull;
    __syncthreads();
    float hi, sc; load_params(umin, umax, h, &hi, &sc);
    unsigned T = Tarr[h];
    unsigned ncand = base[h * NB + T];          // post-scatter inclusive end of bin T
    const unsigned long long* Gh = G + (size_t)h * 65536;
    for (unsigned p = seg * 1024 + tid; p < ncand; p += 16384) {
        unsigned long long pk = Gh[p];
        unsigned u = (unsigned)(pk >> 16);
        float v = u_to_f(u);
        int b = bin_of(v, hi, sc);
        unsigned start = b ? base[h * NB + b - 1] : 0u;
        unsigned end = base[h * NB + b];
        unsigned rank = start;
        for (unsigned j = start; j < end; ++j) rank += (Gh[j] < pk) ? 1u : 0u;
        if (rank < KEEP) {
            stok[h * KEEP + rank] = (unsigned short)(pk & 0xFFFFull);
            long long f = llrintf(v * 16777216.f);
            atomicAdd(&csl[rank >> 6], (unsigned long long)f);
        }
    }
    __syncthreads();
    if (tid < NCOMP && csl[tid]) atomicAdd(&cs_fix[tid], csl[tid]);
}

// ---------------- K4: top-32 chunks via bitonic sort of 256 ------------------
__global__ void k_top32(const unsigned long long* __restrict__ cs_fix,
                        unsigned int* __restrict__ sel) {
    __shared__ unsigned long long key[256];
    int tid = threadIdx.x;
    long long v = (long long)cs_fix[tid];
    unsigned long long bb = (unsigned long long)(v + (1ll << 45));   // strictly positive
    key[tid] = (((1ull << 46) - bb) << 8) | (unsigned)tid;           // asc == (val desc, idx asc)
    __syncthreads();
    for (unsigned k = 2; k <= 256; k <<= 1) {
        for (unsigned j = k >> 1; j > 0; j >>= 1) {
            unsigned ixj = tid ^ j;
            if (ixj > (unsigned)tid) {
                unsigned long long a = key[tid], b = key[ixj];
                bool up = ((tid & k) == 0);
                bool sw = up ? (a > b) : (a < b);
                if (sw) { key[tid] = b; key[ixj] = a; }
            }
            __syncthreads();
        }
    }
    if (tid < NSEL) sel[tid] = (unsigned int)(key[tid] & 0xFFull);
}

// ---------------- K5a: per (head, selected chunk) partial softmax+PV ---------
__global__ void k_attn_part(const float* __restrict__ s, const float* __restrict__ vc,
                            const unsigned short* __restrict__ stok,
                            const unsigned int* __restrict__ sel,
                            float* __restrict__ part) {
    int h = blockIdx.x >> 5, ci = blockIdx.x & 31;
    int tid = threadIdx.x;     // 256
    int g = tid >> 2, b3 = tid & 3;
    int c = (int)sel[ci];
    int t = (c < NCOMP) ? (int)stok[h * KEEP + c * 64 + g]
                        : (PAST + (c - NCOMP) * 64 + g);
    __shared__ float scm[64];
    __shared__ float ex[64];
    __shared__ float vbuf[64][65];
    if (b3 == 0) scm[g] = s[(size_t)h * CT + t] * 0.125f;
    __syncthreads();
    float m = -1e30f;
    for (int j = 0; j < 64; ++j) m = fmaxf(m, scm[j]);
    float e = expf(scm[g] - m);
    const float4* vrow = (const float4*)(vc + (size_t)t * C + h * HS);
#pragma unroll
    for (int it = 0; it < 4; ++it) {
        float4 vv = vrow[it * 4 + b3];
        int d0 = it * 16 + b3 * 4;
        vbuf[g][d0 + 0] = e * vv.x;
        vbuf[g][d0 + 1] = e * vv.y;
        vbuf[g][d0 + 2] = e * vv.z;
        vbuf[g][d0 + 3] = e * vv.w;
    }
    if (b3 == 0) ex[g] = e;
    __syncthreads();
    if (tid < 64) {
        float acc = 0.f;
        for (int g2 = 0; g2 < 64; ++g2) acc += vbuf[g2][tid];
        float* P = part + (size_t)(h * 32 + ci) * 68;
        P[2 + tid] = acc;
        if (tid == 0) {
            float es = 0.f;
            for (int g2 = 0; g2 < 64; ++g2) es += ex[g2];
            P[0] = m;
            P[1] = es;
        }
    }
}

// ---------------- K5b: combine partials + new token -> y ---------------------
__global__ void k_attn_fin(const float* __restrict__ part, const float* __restrict__ q,
                           const float* __restrict__ kn, const float* __restrict__ vn,
                           float* __restrict__ y) {
    int h = blockIdx.x;
    int lane = threadIdx.x;   // 64
    float qd = q[h * HS + lane] * kn[h * HS + lane];
#pragma unroll
    for (int off = 32; off; off >>= 1) qd += __shfl_xor(qd, off);
    float a_new = qd * 0.125f;
    const float* P0 = part + (size_t)h * 32 * 68;
    float m = a_new;
    for (int ci = 0; ci < 32; ++ci) m = fmaxf(m, P0[ci * 68]);
    float den = expf(a_new - m);
    float acc = den * vn[h * HS + lane];
    for (int ci = 0; ci < 32; ++ci) {
        float w = expf(P0[ci * 68] - m);
        den += w * P0[ci * 68 + 1];
        acc += w * P0[ci * 68 + 2 + lane];
    }
    y[h * HS + lane] = acc / den;
}

// ---------------- K6: out = y @ Wo.T -----------------------------------------
__global__ void k_out(const float* __restrict__ Wo, const float* __restrict__ y,
                      float* __restrict__ out) {
    int w = blockIdx.x * (blockDim.x >> 6) + (threadIdx.x >> 6); // 0..1023
    int lane = threadIdx.x & 63;
    const float4* Wrow = (const float4*)(Wo + (size_t)w * C);
    const float4* y4 = (const float4*)y;
    float acc = 0.f;
#pragma unroll
    for (int i = 0; i < 4; ++i) {
        float4 a = Wrow[i * 64 + lane];
        float4 b = y4[i * 64 + lane];
        acc += a.x * b.x + a.y * b.y + a.z * b.z + a.w * b.w;
    }
#pragma unroll
    for (int off = 32; off; off >>= 1) acc += __shfl_xor(acc, off);
    if (lane == 0) out[w] = acc;
}

extern "C" void kernel_launch(void* const* d_in, const int* in_sizes, int n_in,
                              void* d_out, int out_size, void* d_ws, size_t ws_size,
                              hipStream_t stream) {
    const float* x  = (const float*)d_in[0];
    const float* kc = (const float*)d_in[1];
    const float* vc = (const float*)d_in[2];
    const float* Wr = (const float*)d_in[3];
    const float* Wk = (const float*)d_in[4];
    const float* Wv = (const float*)d_in[5];
    const float* Wo = (const float*)d_in[6];
    float* out = (float*)d_out;
    char* ws = (char*)d_ws;

    float* q    = (float*)(ws + 0);
    float* kn   = (float*)(ws + 8192);
    float* vn   = (float*)(ws + 16384);
    float* y    = (float*)(ws + 24576);
    unsigned long long* cs_fix = (unsigned long long*)(ws + 32768);  // 2 KiB
    unsigned int* sel = (unsigned int*)(ws + 40960);
    float* part = (float*)(ws + 49152);                       // 139264 B
    unsigned short* stok = (unsigned short*)(ws + 196608);    // 393216 B
    unsigned* umin = (unsigned*)(ws + 602112);
    unsigned* umax = (unsigned*)(ws + 602176);
    unsigned* Tarr = (unsigned*)(ws + 602240);
    unsigned* base = (unsigned*)(ws + 655360);                // 16*8192*4 = 512 KiB
    float* s = (float*)(ws + 2097152);                        // 4 MiB
    unsigned long long* G = (unsigned long long*)(ws + 6291456); // 8 MiB

    k_proj<<<768, 256, 0, stream>>>(x, Wr, Wk, Wv, q, kn, vn, base, umin, umax, cs_fix);
    k_scores<<<2048, 256, 0, stream>>>(kc, q, s, umin, umax);
    s1_hist<<<64, 1024, 0, stream>>>(s, base, umin, umax);
    s2_scan<<<16, 1024, 0, stream>>>(base, Tarr, s, cs_fix);
    s3_scatter<<<960, 1024, 0, stream>>>(s, base, Tarr, G, umin, umax);
    s4_rank<<<256, 1024, 0, stream>>>(base, Tarr, G, umin, umax, stok, cs_fix);
    k_top32<<<1, 256, 0, stream>>>(cs_fix, sel);
    k_attn_part<<<512, 256, 0, stream>>>(s, vc, stok, sel, part);
    k_attn_fin<<<16, 64, 0, stream>>>(part, q, kn, vn, y);
    k_out<<<256, 256, 0, stream>>>(Wo, y, out);
}